// Round 3
// baseline (614.837 us; speedup 1.0000x reference)
//
#include <hip/hip_runtime.h>

// Problem constants (match reference)
#define B 32
#define S 32
#define N 128
#define U 64
#define E 2
#define NCLS 5

// One fused kernel. grid = 256 blocks (8 per batch element) x 512 threads.
// Each block owns 16 (b,n) rows: 8 waves x 2 rows; lane = feature column.
// h stays in registers for the whole network (row-local).
// Cross-block coupling is ONLY "msg phase needs all of p[b]" -> per-batch
// flag barrier (device-scope release/acquire). Flags start as 0xAA poison,
// sentinel is 1, each slot written once per launch -> no init required.
// Deadlock-safe: 64KB LDS, VGPR<=256 => every block resident (capacity>=grid).

__device__ __forceinline__ void flag_set(int* f) {
    __hip_atomic_store(f, 1, __ATOMIC_RELEASE, __HIP_MEMORY_SCOPE_AGENT);
}
__device__ __forceinline__ int flag_get(const int* f) {
    return __hip_atomic_load(f, __ATOMIC_ACQUIRE, __HIP_MEMORY_SCOPE_AGENT);
}

__global__ __launch_bounds__(512) void k_all(
    const float* __restrict__ x, const int* __restrict__ lens,
    const float* __restrict__ A, const float* __restrict__ Wmsg,
    const float* __restrict__ bmsg, const float* __restrict__ Wg,
    const float* __restrict__ Ug, const float* __restrict__ bg,
    const float* __restrict__ fcw, const float* __restrict__ fcb,
    float* __restrict__ pA, float* __restrict__ pB,
    int* __restrict__ flags,      // [6][B][8]
    int* __restrict__ outflg,     // [B][8]
    float* __restrict__ partial,  // [B][8][NCLS]
    float* __restrict__ out) {
    __shared__ float ps[E * N * U];  // 64 KB: p[b] stage; reused as reduce buf
    int tid = threadIdx.x;
    int wave = tid >> 6, lane = tid & 63;
    int b = blockIdx.x >> 3;
    int j = blockIdx.x & 7;
    int n0 = j * 16 + wave * 2;

    // ---- gather the relevant timestep rows into registers (persist all steps)
    int idx = lens[b] - 1;
    idx = idx < 0 ? 0 : (idx > S - 1 ? S - 1 : idx);
    const float* src = x + ((size_t)(b * S + idx) * N) * U;
    float hv0 = src[(size_t)(n0 + 0) * U + lane];
    float hv1 = src[(size_t)(n0 + 1) * U + lane];

    // ---- p0 = h @ Wmsg[l=0][e] for both edge types -> pA slice
    {
        const float* W0 = Wmsg;
        const float* W1 = Wmsg + U * U;
        float p00 = 0.f, p10 = 0.f, p01 = 0.f, p11 = 0.f;
        for (int u = 0; u < U; ++u) {
            float w0 = W0[u * U + lane], w1 = W1[u * U + lane];
            float h0 = __shfl(hv0, u, 64), h1 = __shfl(hv1, u, 64);
            p00 = fmaf(h0, w0, p00); p10 = fmaf(h1, w0, p10);
            p01 = fmaf(h0, w1, p01); p11 = fmaf(h1, w1, p11);
        }
        pA[(((size_t)b * E + 0) * N + n0 + 0) * U + lane] = p00;
        pA[(((size_t)b * E + 0) * N + n0 + 1) * U + lane] = p10;
        pA[(((size_t)b * E + 1) * N + n0 + 0) * U + lane] = p01;
        pA[(((size_t)b * E + 1) * N + n0 + 1) * U + lane] = p11;
    }
    __syncthreads();  // drains all waves' stores (vmcnt 0) before flag
    if (tid == 0) { __threadfence(); flag_set(&flags[(0 * B + b) * 8 + j]); }

    // ---- 6 propagation steps
    for (int step = 0; step < 6; ++step) {
        int l = (step >= 3) ? 1 : 0;
        const float* pin = (step & 1) ? pB : pA;
        float* pout = (step & 1) ? pA : pB;

        // wait for all 8 blocks of batch b to have written pin
        if (tid < 8) {
            const int* f = &flags[(step * B + b) * 8 + tid];
            while (flag_get(f) != 1) __builtin_amdgcn_s_sleep(4);
        }
        __syncthreads();

        // stage p[b] (all E*N rows) into LDS
        {
            const float4* s4 = (const float4*)(pin + (size_t)b * E * N * U);
            float4* d4 = (float4*)ps;
#pragma unroll
            for (int i = 0; i < 8; i++) d4[tid + i * 512] = s4[tid + i * 512];
        }
        __syncthreads();

        // message aggregation for our 2 rows: av = sum_e A_e[row,:] @ p_e + bm
        float bm = bmsg[l * U + lane];
        float av0 = bm, av1 = bm;
        for (int e = 0; e < E; ++e) {
            const float4* A0 = (const float4*)(A + (((size_t)b * E + e) * N + n0 + 0) * N);
            const float4* A1 = (const float4*)(A + (((size_t)b * E + e) * N + n0 + 1) * N);
            const float* pe = ps + e * N * U;
            for (int m4 = 0; m4 < N / 4; ++m4) {
                float4 a0 = A0[m4], a1 = A1[m4];
                float q0 = pe[(m4 * 4 + 0) * U + lane];
                float q1 = pe[(m4 * 4 + 1) * U + lane];
                float q2 = pe[(m4 * 4 + 2) * U + lane];
                float q3 = pe[(m4 * 4 + 3) * U + lane];
                av0 = fmaf(a0.x, q0, av0); av0 = fmaf(a0.y, q1, av0);
                av0 = fmaf(a0.z, q2, av0); av0 = fmaf(a0.w, q3, av0);
                av1 = fmaf(a1.x, q0, av1); av1 = fmaf(a1.y, q1, av1);
                av1 = fmaf(a1.z, q2, av1); av1 = fmaf(a1.w, q3, av1);
            }
        }

        // gate matmuls (lane = output column)
        const float* Wg0 = Wg + (size_t)l * 3 * U * U;
        const float* Wg1 = Wg0 + U * U;
        const float* Wg2 = Wg1 + U * U;
        const float* Ug0 = Ug + (size_t)l * 3 * U * U;
        const float* Ug1 = Ug0 + U * U;
        const float* Ug2 = Ug1 + U * U;
        float b0 = bg[(l * 3 + 0) * U + lane];
        float b1 = bg[(l * 3 + 1) * U + lane];
        float b2 = bg[(l * 3 + 2) * U + lane];
        float z0 = b0, z1 = b0, r0 = b1, r1 = b1, c0 = b2, c1 = b2;
        for (int u = 0; u < U; ++u) {
            float w0 = Wg0[u * U + lane], w1 = Wg1[u * U + lane], w2 = Wg2[u * U + lane];
            float g0 = Ug0[u * U + lane], g1 = Ug1[u * U + lane];
            float a0 = __shfl(av0, u, 64), a1 = __shfl(av1, u, 64);
            float h0 = __shfl(hv0, u, 64), h1 = __shfl(hv1, u, 64);
            z0 = fmaf(a0, w0, z0); z0 = fmaf(h0, g0, z0);
            z1 = fmaf(a1, w0, z1); z1 = fmaf(h1, g0, z1);
            r0 = fmaf(a0, w1, r0); r0 = fmaf(h0, g1, r0);
            r1 = fmaf(a1, w1, r1); r1 = fmaf(h1, g1, r1);
            c0 = fmaf(a0, w2, c0); c1 = fmaf(a1, w2, c1);
        }
        float rr0 = 1.f / (1.f + expf(-r0));
        float rr1 = 1.f / (1.f + expf(-r1));
        float rh0 = rr0 * hv0, rh1 = rr1 * hv1;
        for (int u = 0; u < U; ++u) {
            float g2 = Ug2[u * U + lane];
            c0 = fmaf(__shfl(rh0, u, 64), g2, c0);
            c1 = fmaf(__shfl(rh1, u, 64), g2, c1);
        }
        float zz0 = 1.f / (1.f + expf(-z0));
        float zz1 = 1.f / (1.f + expf(-z1));
        hv0 = (1.f - zz0) * hv0 + zz0 * tanhf(c0);
        hv1 = (1.f - zz1) * hv1 + zz1 * tanhf(c1);

        // p' = h' @ Wmsg[lnext] for next step
        if (step < 5) {
            int lnext = (step + 1 >= 3) ? 1 : 0;
            const float* W0 = Wmsg + (size_t)(lnext * E + 0) * U * U;
            const float* W1 = Wmsg + (size_t)(lnext * E + 1) * U * U;
            float p00 = 0.f, p10 = 0.f, p01 = 0.f, p11 = 0.f;
            for (int u = 0; u < U; ++u) {
                float w0 = W0[u * U + lane], w1 = W1[u * U + lane];
                float h0 = __shfl(hv0, u, 64), h1 = __shfl(hv1, u, 64);
                p00 = fmaf(h0, w0, p00); p10 = fmaf(h1, w0, p10);
                p01 = fmaf(h0, w1, p01); p11 = fmaf(h1, w1, p11);
            }
            pout[(((size_t)b * E + 0) * N + n0 + 0) * U + lane] = p00;
            pout[(((size_t)b * E + 0) * N + n0 + 1) * U + lane] = p10;
            pout[(((size_t)b * E + 1) * N + n0 + 0) * U + lane] = p01;
            pout[(((size_t)b * E + 1) * N + n0 + 1) * U + lane] = p11;
            __syncthreads();  // drain all waves' p' stores
            if (tid == 0) { __threadfence(); flag_set(&flags[((step + 1) * B + b) * 8 + j]); }
        }
    }

    // ---- fused classification: block-partial of max_n relu(h') @ fc_w
    float lg0[NCLS], lg1[NCLS];
    float rv0 = hv0 > 0.f ? hv0 : 0.f;
    float rv1 = hv1 > 0.f ? hv1 : 0.f;
#pragma unroll
    for (int c = 0; c < NCLS; c++) {
        float w = fcw[lane * NCLS + c];
        lg0[c] = rv0 * w;
        lg1[c] = rv1 * w;
    }
#pragma unroll
    for (int off = 32; off; off >>= 1) {
#pragma unroll
        for (int c = 0; c < NCLS; c++) {
            lg0[c] += __shfl_xor(lg0[c], off, 64);
            lg1[c] += __shfl_xor(lg1[c], off, 64);
        }
    }
    __syncthreads();  // everyone done with ps (msg stage); reuse as reduce buf
    if (lane == 0) {
#pragma unroll
        for (int c = 0; c < NCLS; c++) ps[wave * NCLS + c] = fmaxf(lg0[c], lg1[c]);
    }
    __syncthreads();
    if (tid < NCLS) {
        float m = ps[tid];
        for (int w = 1; w < 8; ++w) m = fmaxf(m, ps[w * NCLS + tid]);
        partial[(size_t)(b * 8 + j) * NCLS + tid] = m;
    }
    if (tid == 0) { __threadfence(); flag_set(&outflg[b * 8 + j]); }

    // ---- block j==0 of each batch reduces the 8 partials and writes out
    if (j == 0 && wave == 0) {
        if (lane < 8) {
            const int* f = &outflg[b * 8 + lane];
            while (flag_get(f) != 1) __builtin_amdgcn_s_sleep(4);
        }
        if (lane < NCLS) {
            float m = -3.4e38f;
            for (int jj = 0; jj < 8; ++jj)
                m = fmaxf(m, partial[(size_t)(b * 8 + jj) * NCLS + lane]);
            out[b * NCLS + lane] = m + fcb[lane];
        }
    }
}

// ---------------------------------------------------------------------------
extern "C" void kernel_launch(void* const* d_in, const int* in_sizes, int n_in,
                              void* d_out, int out_size, void* d_ws, size_t ws_size,
                              hipStream_t stream) {
    const float* x    = (const float*)d_in[0];
    const int*   lens = (const int*)d_in[1];
    const float* A    = (const float*)d_in[2];
    const float* Wmsg = (const float*)d_in[3];
    const float* bmsg = (const float*)d_in[4];
    const float* Wg   = (const float*)d_in[5];
    const float* Ug   = (const float*)d_in[6];
    const float* bg   = (const float*)d_in[7];
    const float* fcw  = (const float*)d_in[8];
    const float* fcb  = (const float*)d_in[9];
    float* out = (float*)d_out;

    float* pA      = (float*)d_ws;                   // [B][E][N][U]
    float* pB      = pA + (size_t)B * E * N * U;     // [B][E][N][U]
    float* partial = pB + (size_t)B * E * N * U;     // [B][8][NCLS]
    int*   flags   = (int*)(partial + (size_t)B * 8 * NCLS);  // [6][B][8]
    int*   outflg  = flags + 6 * B * 8;              // [B][8]

    k_all<<<B * 8, 512, 0, stream>>>(x, lens, A, Wmsg, bmsg, Wg, Ug, bg, fcw, fcb,
                                     pA, pB, flags, outflg, partial, out);
}